// Round 7
// baseline (247.817 us; speedup 1.0000x reference)
//
#include <hip/hip_runtime.h>

// MN neuron forward sim: T=1000 sequential steps, 64x512 independent chains.
// Round 7: SHORTEN THE DEPENDENCE CYCLE. R2/R5/R6 all ~85us with totally
// different memory pipelines => compute-latency-bound: 16-op loop-carried
// chain x ~12 cyc true dependent-VALU latency = ~197 cyc/step. Wall time =
// 1000 x chain latency (TLP/ILP cannot help a serial recurrence).
// Fix: 2-way spike speculation moves i-decays, input sums, G*(V-EL) and
// B*(Thr-TINF) off the cycle; one cndmask each remains. Cycle 16 -> 11 ops:
//   cmp -> sel -> s -> d -> V -> e2 -> u -> s2 -> d2 -> Thr -> diff -> cmp
// All transforms are bit-exact: same selector distributes over per-variant
// computation; spike-V gives G*(VR-EL)=G*(+0)=+0 exactly (VR==EL).
// Memory skeleton identical to R6 (proven absmax=0.0).
// CORRECTNESS: binary spike output => bit-exact f32 vs numpy ref:
//   exact reference op order, no FMA contraction, selects for spike resets.

#define T_STEPS 1000
#define B_DIM 64
#define N_DIM 512
#define BN (B_DIM * N_DIM)   // 32768

#define K_CHUNK 20
#define NCHUNK (T_STEPS / K_CHUNK)   // 50
#define NBUF 8                       // ring depth (chunks)

// f32-rounded constants
#define C_DT   0.01f
#define C_EL   (-0.07f)
#define C_VR   (-0.07f)
#define C_TR   (-0.06f)
#define C_TINF (-0.05f)
#define C_B    12.77495288848877f
#define C_G    45.24007797241211f
#define C_K1   200.0f
#define C_K2   20.0f
#define C_R1   0.3858567178249359f
#define C_R2   (-1.1421641111373901f)

typedef const __attribute__((address_space(1))) void* gp_t;
typedef __attribute__((address_space(3))) void* lp_t;
typedef __attribute__((address_space(3))) float* lpf_t;

__global__ __launch_bounds__(128) void mn_neuron_kernel(
    const float* __restrict__ x, const float* __restrict__ linear,
    const float* __restrict__ a, const float* __restrict__ A1,
    const float* __restrict__ A2, float* __restrict__ out)
{
#pragma clang fp contract(off)
    // lds[buf][t_in_chunk][lane]  -- 8 x 5 KB ring
    __shared__ float lds[NBUF][K_CHUNK][64];

    const int lane = threadIdx.x & 63;
    const int wid  = threadIdx.x >> 6;     // 0 = consumer, 1 = producer
    const int blk  = blockIdx.x;

    if (wid == 1) {
        // ---- producer ---- (identical to R6)
        const float* pl = x + (size_t)(lane >> 4) * BN
                            + (size_t)blk * 64 + (size_t)(lane & 15) * 4;

        auto issue_chunk = [&](int ch) {
            const float* pc = pl + (size_t)(ch * K_CHUNK) * BN;
            float* dst = &lds[ch & (NBUF - 1)][0][0];
#pragma unroll
            for (int s = 0; s < K_CHUNK / 4; ++s) {
                __builtin_amdgcn_global_load_lds(
                    (gp_t)(pc + (size_t)(s * 4) * BN),
                    (lp_t)(dst + s * 4 * 64), 16, 0, 0);
            }
        };

        for (int ch = 0; ch < NBUF - 1; ++ch) issue_chunk(ch);
        asm volatile("s_waitcnt vmcnt(30)" ::: "memory");  // chunk 0 landed
        __builtin_amdgcn_s_barrier();                      // barrier #1

        for (int c = 0; c <= NCHUNK - NBUF; ++c) {
            issue_chunk(c + NBUF - 1);
            asm volatile("s_waitcnt vmcnt(30)" ::: "memory");
            __builtin_amdgcn_s_barrier();
        }
        asm volatile("s_waitcnt vmcnt(25)" ::: "memory");
        __builtin_amdgcn_s_barrier();
        asm volatile("s_waitcnt vmcnt(20)" ::: "memory");
        __builtin_amdgcn_s_barrier();
        asm volatile("s_waitcnt vmcnt(15)" ::: "memory");
        __builtin_amdgcn_s_barrier();
        asm volatile("s_waitcnt vmcnt(10)" ::: "memory");
        __builtin_amdgcn_s_barrier();
        asm volatile("s_waitcnt vmcnt(5)" ::: "memory");
        __builtin_amdgcn_s_barrier();
        asm volatile("s_waitcnt vmcnt(0)" ::: "memory");
        __builtin_amdgcn_s_barrier();
        __builtin_amdgcn_s_barrier();                      // final
    } else {
        // ---- consumer ----
        const int idx = blk * 64 + lane;       // b*N + n
        const int n   = idx & (N_DIM - 1);

        const float lin = linear[n];
        const float av  = a[n];
        const float A1v = A1[n];
        const float A2v = A2[n];

        // ---- recurrence state (speculative form) ----
        // sb     : spike at previous step
        // V, Thr : pre-reset V_t / Thr_t of previous step
        // Thrm   : max(Thr, TR)                    (spike variant)
        // P1,Q1  : decay candidates for i1 at CURRENT step (no-spike / spike)
        // P2,Q2  : same for i2
        // sumP,sumQ: (p + P1) + P2  /  (p + Q1) + Q2  for current step
        // gA     : G*(V - EL)        (no-spike; spike variant == +0 exactly)
        // bwA,bwB: B*(Thr - TINF) / B*(Thrm - TINF)
        bool  sb   = false;
        float V    = C_EL;
        float Thr  = C_TINF;
        float Thrm = C_TINF;
        float P1 = 0.0f, Q1 = 0.0f, P2 = 0.0f, Q2 = 0.0f;
        float sumP = 0.0f, sumQ = 0.0f;            // re-formed at chunk top
        float gA  = C_G * (C_EL - C_EL);           // == +0, as ref step 0
        float bwA = C_B * (C_TINF - C_TINF);       // == +0, as ref step 0
        float bwB = bwA;

        float* op = out + idx;

        __builtin_amdgcn_s_barrier();          // barrier #1 (chunk 0 ready)

        for (int c = 0; c < NCHUNK; ++c) {
            lpf_t lptr = (lpf_t)&lds[c & (NBUF - 1)][0][lane];

            // ALL 20 chunk loads in ONE asm block, waitcnt inside.
            float xv[K_CHUNK];
            asm volatile(
                "ds_read_b32 %0,  %20 offset:0\n\t"
                "ds_read_b32 %1,  %20 offset:256\n\t"
                "ds_read_b32 %2,  %20 offset:512\n\t"
                "ds_read_b32 %3,  %20 offset:768\n\t"
                "ds_read_b32 %4,  %20 offset:1024\n\t"
                "ds_read_b32 %5,  %20 offset:1280\n\t"
                "ds_read_b32 %6,  %20 offset:1536\n\t"
                "ds_read_b32 %7,  %20 offset:1792\n\t"
                "ds_read_b32 %8,  %20 offset:2048\n\t"
                "ds_read_b32 %9,  %20 offset:2304\n\t"
                "ds_read_b32 %10, %20 offset:2560\n\t"
                "ds_read_b32 %11, %20 offset:2816\n\t"
                "ds_read_b32 %12, %20 offset:3072\n\t"
                "ds_read_b32 %13, %20 offset:3328\n\t"
                "ds_read_b32 %14, %20 offset:3584\n\t"
                "ds_read_b32 %15, %20 offset:3840\n\t"
                "ds_read_b32 %16, %20 offset:4096\n\t"
                "ds_read_b32 %17, %20 offset:4352\n\t"
                "ds_read_b32 %18, %20 offset:4608\n\t"
                "ds_read_b32 %19, %20 offset:4864\n\t"
                "s_waitcnt lgkmcnt(0)"
                : "=&v"(xv[0]),  "=&v"(xv[1]),  "=&v"(xv[2]),  "=&v"(xv[3]),
                  "=&v"(xv[4]),  "=&v"(xv[5]),  "=&v"(xv[6]),  "=&v"(xv[7]),
                  "=&v"(xv[8]),  "=&v"(xv[9]),  "=&v"(xv[10]), "=&v"(xv[11]),
                  "=&v"(xv[12]), "=&v"(xv[13]), "=&v"(xv[14]), "=&v"(xv[15]),
                  "=&v"(xv[16]), "=&v"(xv[17]), "=&v"(xv[18]), "=&v"(xv[19])
                : "v"(lptr));

            __builtin_amdgcn_s_barrier();      // release buffer

            // chunk-top: (re)form the speculative sums for step 0 of this
            // chunk (last step of prev chunk couldn't see this chunk's x).
            {
                float p0 = lin * xv[0];
                sumP = (p0 + P1) + P2;
                sumQ = (p0 + Q1) + Q2;
            }

#pragma unroll
            for (int j = 0; j < K_CHUNK; ++j) {
                // ---- the 11-op dependence cycle ----
                float r   = sb ? sumQ : sumP;   // p + i1' + i2'
                float gs  = sb ? 0.0f : gA;     // G*(V_rst - EL)
                float s   = r - gs;
                float d   = C_DT * s;
                float Vs  = sb ? C_VR : V;      // V_rst
                float Vn  = Vs + d;             // V_t
                float e2  = Vn - C_EL;
                float u   = av * e2;
                float bws = sb ? bwB : bwA;     // B*(Thr_rst - TINF)
                float s2  = u - bws;
                float d2  = C_DT * s2;
                float Ts  = sb ? Thrm : Thr;    // Thr_rst
                float Tn  = Ts + d2;            // Thr_t
                float diff = Vn - Tn;
                bool  sbn  = diff > 0.0f;       // spike at step t

                float spk = sbn ? 1.0f : 0.0f;
                __builtin_nontemporal_store(spk, op);
                op += BN;

                // ---- off-path: speculative prep for step t+1 ----
                float D1  = sb ? Q1 : P1;       // i1'_t (decayed, pre-reset)
                float D2  = sb ? Q2 : P2;
                float i1r = (C_R1 * D1) + A1v;  // spike-reset variants
                float i2r = (C_R2 * D2) + A2v;
                P1 = D1  - (C_K1 * D1)  * C_DT; // decay candidates for t+1
                Q1 = i1r - (C_K1 * i1r) * C_DT;
                P2 = D2  - (C_K2 * D2)  * C_DT;
                Q2 = i2r - (C_K2 * i2r) * C_DT;
                if (j < K_CHUNK - 1) {
                    float pn = lin * xv[j + 1];
                    sumP = (pn + P1) + P2;
                    sumQ = (pn + Q1) + Q2;
                }
                gA   = C_G * e2;                // == G*(Vn - EL), bit-exact
                Thrm = fmaxf(Tn, C_TR);
                float wA = Tn   - C_TINF;
                float wB = Thrm - C_TINF;
                bwA  = C_B * wA;
                bwB  = C_B * wB;
                V = Vn; Thr = Tn; sb = sbn;
            }
        }
    }
}

extern "C" void kernel_launch(void* const* d_in, const int* in_sizes, int n_in,
                              void* d_out, int out_size, void* d_ws, size_t ws_size,
                              hipStream_t stream) {
    const float* x      = (const float*)d_in[0];
    const float* linear = (const float*)d_in[1];
    const float* a      = (const float*)d_in[2];
    const float* A1     = (const float*)d_in[3];
    const float* A2     = (const float*)d_in[4];
    float* out = (float*)d_out;

    // 512 blocks x 128 threads (1 consumer wave + 1 producer wave each)
    mn_neuron_kernel<<<BN / 64, 128, 0, stream>>>(x, linear, a, A1, A2, out);
}